// Round 4
// baseline (528.427 us; speedup 1.0000x reference)
//
#include <hip/hip_runtime.h>
#include <hip/hip_bf16.h>

// N=16384 queries, C=1024 classes, D=4096.
// sims = l2norm(hvs) @ l2norm(am)^T ; preds = argmax ; eta = (sims[:,1]-sims[:,0])/4 + 0.5
// R4: phase-split K-loop (4 phases/K-step, per-phase barrier + lgkmcnt(0) +
// setprio MFMA cluster), counted vmcnt(8) at tile boundary. 256x256 tile,
// 8 waves, 3-term bf16-split MFMA, fused argmax epilogue.

#define NQ 16384
#define NC 1024
#define DK 4096
#define BKS 32

typedef __attribute__((ext_vector_type(8))) short short8;
typedef __attribute__((ext_vector_type(4))) float f32x4;
typedef unsigned short ushort_t;

__device__ __forceinline__ unsigned short bf16_rne(float x) {
    unsigned int u = __float_as_uint(x);
    u += 0x7FFFu + ((u >> 16) & 1u);
    return (unsigned short)(u >> 16);
}
__device__ __forceinline__ float bf16_f32(unsigned short h) {
    return __uint_as_float(((unsigned int)h) << 16);
}

#define GLDS(g, l)                                                                       \
    __builtin_amdgcn_global_load_lds((const __attribute__((address_space(1))) void*)(g), \
                                     (__attribute__((address_space(3))) void*)(l), 16, 0, 0)

// ---------------- fused row-norm + normalize + bf16 hi/lo split ----------------
__global__ void __launch_bounds__(256) norm_split_kernel(const float* __restrict__ x,
                                                         ushort_t* __restrict__ hi,
                                                         ushort_t* __restrict__ lo) {
    const int row = blockIdx.x;
    const int tid = threadIdx.x;
    const float4* x4 = (const float4*)(x + (size_t)row * DK);

    float4 v[4];
    float ss = 0.f;
#pragma unroll
    for (int i = 0; i < 4; ++i) {
        v[i] = x4[tid * 4 + i];
        ss += v[i].x * v[i].x + v[i].y * v[i].y + v[i].z * v[i].z + v[i].w * v[i].w;
    }
#pragma unroll
    for (int off = 32; off; off >>= 1) ss += __shfl_xor(ss, off, 64);
    __shared__ float wsum[4];
    const int lane = tid & 63, w = tid >> 6;
    if (lane == 0) wsum[w] = ss;
    __syncthreads();
    const float tot = wsum[0] + wsum[1] + wsum[2] + wsum[3];
    const float r = 1.0f / fmaxf(sqrtf(tot), 1e-8f);

    ushort_t hbuf[16], lbuf[16];
#pragma unroll
    for (int i = 0; i < 4; ++i) {
        const float xs[4] = {v[i].x * r, v[i].y * r, v[i].z * r, v[i].w * r};
#pragma unroll
        for (int j = 0; j < 4; ++j) {
            const unsigned short h = bf16_rne(xs[j]);
            hbuf[i * 4 + j] = h;
            lbuf[i * 4 + j] = bf16_rne(xs[j] - bf16_f32(h));
        }
    }
    ushort_t* hp = hi + (size_t)row * DK + tid * 16;
    ushort_t* lp = lo + (size_t)row * DK + tid * 16;
    *(short8*)hp = *(short8*)hbuf;
    *(short8*)(hp + 8) = *(short8*)(hbuf + 8);
    *(short8*)lp = *(short8*)lbuf;
    *(short8*)(lp + 8) = *(short8*)(lbuf + 8);
}

// ---------------- 256x256 3-term split GEMM, phase-split schedule ----------------
__global__ void __launch_bounds__(512, 2) gemm_fused_kernel(const ushort_t* __restrict__ Ah,
                                                            const ushort_t* __restrict__ Al,
                                                            const ushort_t* __restrict__ Bh,
                                                            const ushort_t* __restrict__ Bl,
                                                            float2* __restrict__ cand,
                                                            float* __restrict__ s01) {
    __shared__ __align__(16) ushort_t lA[2][2][256 * BKS];  // [buf][hi/lo] 64 KB
    __shared__ __align__(16) ushort_t lB[2][2][256 * BKS];  // 64 KB

    const int tid = threadIdx.x;
    const int lane = tid & 63;
    const int w = tid >> 6;   // 0..7
    const int wm = w >> 2;    // 0..1
    const int wn = w & 3;     // 0..3

    // bijective XCD swizzle: 4 bx-blocks sharing a by-panel land on one XCD
    const int id = blockIdx.x;             // 0..255
    const int xcd = id & 7;
    const int slot = id >> 3;              // 0..31
    const int by = xcd * 8 + (slot >> 2);  // 0..63
    const int bx = slot & 3;               // 0..3

    // staging: per matrix-half, tile = 256 rows x 4 slots(16B) = 1024 chunks; 2/thread
    const int q0 = tid, q1 = tid + 512;
    const int row0 = q0 >> 2, row1 = q1 >> 2;
    const int gs0 = (q0 & 3) ^ ((row0 >> 1) & 3);
    const int gs1 = (q1 & 3) ^ ((row1 >> 1) & 3);
    const size_t offA0 = (size_t)(by * 256 + row0) * DK + gs0 * 8;
    const size_t offA1 = (size_t)(by * 256 + row1) * DK + gs1 * 8;
    const size_t offB0 = (size_t)(bx * 256 + row0) * DK + gs0 * 8;
    const size_t offB1 = (size_t)(bx * 256 + row1) * DK + gs1 * 8;

    f32x4 acc[8][4];
#pragma unroll
    for (int m = 0; m < 8; ++m)
#pragma unroll
        for (int n = 0; n < 4; ++n) acc[m][n] = (f32x4){0.f, 0.f, 0.f, 0.f};

    const int r0 = lane & 15;
    const int rg = lane >> 4;  // k-octet

    // LDS frag offsets (shorts), swizzle-matched to staged layout
    int aoff[8], boff[4];
#pragma unroll
    for (int m = 0; m < 8; ++m) {
        const int row = wm * 128 + m * 16 + r0;
        aoff[m] = row * BKS + (rg ^ ((row >> 1) & 3)) * 8;
    }
#pragma unroll
    for (int n = 0; n < 4; ++n) {
        const int col = wn * 64 + n * 16 + r0;
        boff[n] = col * BKS + (rg ^ ((col >> 1) & 3)) * 8;
    }

    auto stage = [&](int buf, int kt) {
        const size_t ko = (size_t)kt * BKS;
        GLDS(Ah + offA0 + ko, &lA[buf][0][q0 * 8]);
        GLDS(Al + offA0 + ko, &lA[buf][1][q0 * 8]);
        GLDS(Bh + offB0 + ko, &lB[buf][0][q0 * 8]);
        GLDS(Bl + offB0 + ko, &lB[buf][1][q0 * 8]);
        GLDS(Ah + offA1 + ko, &lA[buf][0][q1 * 8]);
        GLDS(Al + offA1 + ko, &lA[buf][1][q1 * 8]);
        GLDS(Bh + offB1 + ko, &lB[buf][0][q1 * 8]);
        GLDS(Bl + offB1 + ko, &lB[buf][1][q1 * 8]);
    };

    stage(0, 0);
    const int nK = DK / BKS;  // 128

    for (int kt = 0; kt < nK; ++kt) {
        const int cur = kt & 1;
        const ushort_t* __restrict__ pAh = &lA[cur][0][0];
        const ushort_t* __restrict__ pAl = &lA[cur][1][0];
        const ushort_t* __restrict__ pBh = &lB[cur][0][0];
        const ushort_t* __restrict__ pBl = &lB[cur][1][0];

        // END barrier: all waves have register-completed every read of buf cur^1
        __builtin_amdgcn_s_barrier();
        if (kt + 1 < nK) {
            stage(cur ^ 1, kt + 1);                           // 8 new loads in flight
            asm volatile("s_waitcnt vmcnt(8)" ::: "memory");  // cur's 8 (from kt-1) done
        } else {
            asm volatile("s_waitcnt vmcnt(0)" ::: "memory");
        }
        __builtin_amdgcn_s_barrier();  // BEGIN: buf cur staged by ALL waves

        // ---- phase 0: B frags + A group 0 (m=0,1) ----
        short8 bh[4], bl[4], ah0, al0, ah1, al1;
#pragma unroll
        for (int n = 0; n < 4; ++n) {
            bh[n] = *(const short8*)&pBh[boff[n]];
            bl[n] = *(const short8*)&pBl[boff[n]];
        }
        ah0 = *(const short8*)&pAh[aoff[0]];
        al0 = *(const short8*)&pAl[aoff[0]];
        ah1 = *(const short8*)&pAh[aoff[1]];
        al1 = *(const short8*)&pAl[aoff[1]];
        asm volatile("s_waitcnt lgkmcnt(0)" ::: "memory");
        __builtin_amdgcn_sched_barrier(0);
        __builtin_amdgcn_s_setprio(1);
#pragma unroll
        for (int n = 0; n < 4; ++n) {
            acc[0][n] = __builtin_amdgcn_mfma_f32_16x16x32_bf16(ah0, bh[n], acc[0][n], 0, 0, 0);
            acc[0][n] = __builtin_amdgcn_mfma_f32_16x16x32_bf16(ah0, bl[n], acc[0][n], 0, 0, 0);
            acc[0][n] = __builtin_amdgcn_mfma_f32_16x16x32_bf16(al0, bh[n], acc[0][n], 0, 0, 0);
            acc[1][n] = __builtin_amdgcn_mfma_f32_16x16x32_bf16(ah1, bh[n], acc[1][n], 0, 0, 0);
            acc[1][n] = __builtin_amdgcn_mfma_f32_16x16x32_bf16(ah1, bl[n], acc[1][n], 0, 0, 0);
            acc[1][n] = __builtin_amdgcn_mfma_f32_16x16x32_bf16(al1, bh[n], acc[1][n], 0, 0, 0);
        }
        __builtin_amdgcn_s_setprio(0);
        __builtin_amdgcn_s_barrier();

        // ---- phases 1..3: A groups (m=2g,2g+1) ----
#pragma unroll
        for (int g = 1; g < 4; ++g) {
            short8 ahA = *(const short8*)&pAh[aoff[2 * g]];
            short8 alA = *(const short8*)&pAl[aoff[2 * g]];
            short8 ahB = *(const short8*)&pAh[aoff[2 * g + 1]];
            short8 alB = *(const short8*)&pAl[aoff[2 * g + 1]];
            asm volatile("s_waitcnt lgkmcnt(0)" ::: "memory");
            __builtin_amdgcn_sched_barrier(0);
            __builtin_amdgcn_s_setprio(1);
#pragma unroll
            for (int n = 0; n < 4; ++n) {
                acc[2 * g][n] = __builtin_amdgcn_mfma_f32_16x16x32_bf16(ahA, bh[n], acc[2 * g][n], 0, 0, 0);
                acc[2 * g][n] = __builtin_amdgcn_mfma_f32_16x16x32_bf16(ahA, bl[n], acc[2 * g][n], 0, 0, 0);
                acc[2 * g][n] = __builtin_amdgcn_mfma_f32_16x16x32_bf16(alA, bh[n], acc[2 * g][n], 0, 0, 0);
                acc[2 * g + 1][n] = __builtin_amdgcn_mfma_f32_16x16x32_bf16(ahB, bh[n], acc[2 * g + 1][n], 0, 0, 0);
                acc[2 * g + 1][n] = __builtin_amdgcn_mfma_f32_16x16x32_bf16(ahB, bl[n], acc[2 * g + 1][n], 0, 0, 0);
                acc[2 * g + 1][n] = __builtin_amdgcn_mfma_f32_16x16x32_bf16(alB, bh[n], acc[2 * g + 1][n], 0, 0, 0);
            }
            __builtin_amdgcn_s_setprio(0);
            if (g < 3) __builtin_amdgcn_s_barrier();
        }
    }

    // epilogue: C/D layout col=lane&15, row=(lane>>4)*4+j [m89]
    const int rowb = by * 256 + wm * 128;
#pragma unroll
    for (int m = 0; m < 8; ++m) {
#pragma unroll
        for (int j = 0; j < 4; ++j) {
            float best = acc[m][0][j];
            int bidx = wn * 64 + r0;
#pragma unroll
            for (int n = 1; n < 4; ++n) {
                const float v = acc[m][n][j];
                const int c = wn * 64 + n * 16 + r0;
                if (v > best) { best = v; bidx = c; }
            }
#pragma unroll
            for (int off = 1; off < 16; off <<= 1) {
                const float ov = __shfl_xor(best, off, 64);
                const int oi = __shfl_xor(bidx, off, 64);
                if (ov > best || (ov == best && oi < bidx)) { best = ov; bidx = oi; }
            }
            const int row = rowb + m * 16 + rg * 4 + j;
            if (r0 == 0)
                cand[(size_t)row * 16 + bx * 4 + wn] = make_float2(best, (float)(bx * 256 + bidx));
            if (bx == 0 && wn == 0 && r0 < 2) s01[row * 2 + r0] = acc[m][0][j];
        }
    }
}

// ---------------- final reduce: 16 candidates/row + eta ----------------
__global__ void __launch_bounds__(256) finalize_kernel(const float2* __restrict__ cand,
                                                       const float* __restrict__ s01,
                                                       float* __restrict__ out) {
    const int row = blockIdx.x * 256 + threadIdx.x;
    const float2* c = cand + (size_t)row * 16;
    float best = c[0].x;
    float bi = c[0].y;
#pragma unroll
    for (int i = 1; i < 16; ++i) {
        const float2 p = c[i];
        if (p.x > best) { best = p.x; bi = p.y; }  // ascending col blocks: strict > keeps first
    }
    out[row] = bi;
    out[NQ + row] = (s01[row * 2 + 1] - s01[row * 2 + 0]) * 0.25f + 0.5f;
}

extern "C" void kernel_launch(void* const* d_in, const int* in_sizes, int n_in,
                              void* d_out, int out_size, void* d_ws, size_t ws_size,
                              hipStream_t stream) {
    const float* hvs = (const float*)d_in[0];  // [16384,4096] f32
    const float* am  = (const float*)d_in[1];  // [1024,4096] f32
    float* out = (float*)d_out;                // [preds | eta]

    ushort_t* Bh = (ushort_t*)d_ws;
    ushort_t* Bl = Bh + (size_t)NC * DK;
    ushort_t* Ah = Bl + (size_t)NC * DK;
    ushort_t* Al = Ah + (size_t)NQ * DK;
    float2* cand = (float2*)(Al + (size_t)NQ * DK);  // 16384*16 float2 = 2 MB
    float* s01 = (float*)(cand + (size_t)NQ * 16);   // 16384*2 f32

    norm_split_kernel<<<NC, 256, 0, stream>>>(am, Bh, Bl);
    norm_split_kernel<<<NQ, 256, 0, stream>>>(hvs, Ah, Al);
    gemm_fused_kernel<<<256, 512, 0, stream>>>(Ah, Al, Bh, Bl, cand, s01);
    finalize_kernel<<<NQ / 256, 256, 0, stream>>>(cand, s01, out);
}

// Round 5
// 442.185 us; speedup vs baseline: 1.1950x; 1.1950x over previous
//
#include <hip/hip_runtime.h>
#include <hip/hip_bf16.h>

// N=16384 queries, C=1024 classes, D=4096.
// sims = l2norm(hvs) @ l2norm(am)^T ; preds = argmax ; eta = (sims[:,1]-sims[:,0])/4 + 0.5
// R5: two-pass. Pass 1: 1-term bf16 GEMM (BK=64, R3 sync skeleton) + fused
// per-block top-2. Rows with top-2 gap < TAU are re-checked with the proven
// 3-term bf16-split GEMM on a compacted worklist. eta from pass-1 sims.

#define NQ 16384
#define NC 1024
#define DK 4096
#define TAU 4e-4f

typedef __attribute__((ext_vector_type(8))) short short8;
typedef __attribute__((ext_vector_type(4))) float f32x4;
typedef unsigned short ushort_t;

__device__ __forceinline__ unsigned short bf16_rne(float x) {
    unsigned int u = __float_as_uint(x);
    u += 0x7FFFu + ((u >> 16) & 1u);
    return (unsigned short)(u >> 16);
}
__device__ __forceinline__ float bf16_f32(unsigned short h) {
    return __uint_as_float(((unsigned int)h) << 16);
}

#define GLDS(g, l)                                                                       \
    __builtin_amdgcn_global_load_lds((const __attribute__((address_space(1))) void*)(g), \
                                     (__attribute__((address_space(3))) void*)(l), 16, 0, 0)

// ---------------- fused row-norm + normalize + bf16 hi/lo split ----------------
__global__ void __launch_bounds__(256) norm_split_kernel(const float* __restrict__ x,
                                                         ushort_t* __restrict__ hi,
                                                         ushort_t* __restrict__ lo) {
    const int row = blockIdx.x;
    const int tid = threadIdx.x;
    const float4* x4 = (const float4*)(x + (size_t)row * DK);

    float4 v[4];
    float ss = 0.f;
#pragma unroll
    for (int i = 0; i < 4; ++i) {
        v[i] = x4[tid * 4 + i];
        ss += v[i].x * v[i].x + v[i].y * v[i].y + v[i].z * v[i].z + v[i].w * v[i].w;
    }
#pragma unroll
    for (int off = 32; off; off >>= 1) ss += __shfl_xor(ss, off, 64);
    __shared__ float wsum[4];
    const int lane = tid & 63, w = tid >> 6;
    if (lane == 0) wsum[w] = ss;
    __syncthreads();
    const float tot = wsum[0] + wsum[1] + wsum[2] + wsum[3];
    const float r = 1.0f / fmaxf(sqrtf(tot), 1e-8f);

    ushort_t hbuf[16], lbuf[16];
#pragma unroll
    for (int i = 0; i < 4; ++i) {
        const float xs[4] = {v[i].x * r, v[i].y * r, v[i].z * r, v[i].w * r};
#pragma unroll
        for (int j = 0; j < 4; ++j) {
            const unsigned short h = bf16_rne(xs[j]);
            hbuf[i * 4 + j] = h;
            lbuf[i * 4 + j] = bf16_rne(xs[j] - bf16_f32(h));
        }
    }
    ushort_t* hp = hi + (size_t)row * DK + tid * 16;
    ushort_t* lp = lo + (size_t)row * DK + tid * 16;
    *(short8*)hp = *(short8*)hbuf;
    *(short8*)(hp + 8) = *(short8*)(hbuf + 8);
    *(short8*)lp = *(short8*)lbuf;
    *(short8*)(lp + 8) = *(short8*)(lbuf + 8);
}

// ---------------- pass 1: 1-term bf16 GEMM, BK=64, fused top-2 ----------------
// 256x256 tile, 8 waves (2Mx4N, each 128x64), dbuf LDS 128 KB, issue-early
// staging + counted vmcnt(8), 8-slot XOR swizzle (gs = slot ^ (row&7)).
__global__ void __launch_bounds__(512, 2) gemm1_kernel(const ushort_t* __restrict__ Ah,
                                                       const ushort_t* __restrict__ Bh,
                                                       float4* __restrict__ cand,
                                                       float* __restrict__ s01) {
    __shared__ __align__(16) ushort_t lA[2][256 * 64];  // 64 KB
    __shared__ __align__(16) ushort_t lB[2][256 * 64];  // 64 KB

    const int tid = threadIdx.x;
    const int lane = tid & 63;
    const int w = tid >> 6;   // 0..7
    const int wm = w >> 2;    // 0..1
    const int wn = w & 3;     // 0..3

    // bijective XCD swizzle: 4 bx-blocks sharing a by-panel land on one XCD
    const int id = blockIdx.x;             // 0..255
    const int xcd = id & 7;
    const int slot = id >> 3;              // 0..31
    const int by = xcd * 8 + (slot >> 2);  // 0..63
    const int bx = slot & 3;               // 0..3

    // staging: per operand tile = 256 rows x 8 slots(16B) = 2048 chunks; 4/thread
    int srow[4], sq[4];
    size_t offA[4], offB[4];
#pragma unroll
    for (int i = 0; i < 4; ++i) {
        const int q = tid + i * 512;
        sq[i] = q;
        srow[i] = q >> 3;
        const int gs = (q & 7) ^ (srow[i] & 7);
        offA[i] = (size_t)(by * 256 + srow[i]) * DK + gs * 8;
        offB[i] = (size_t)(bx * 256 + srow[i]) * DK + gs * 8;
    }

    f32x4 acc[8][4];
#pragma unroll
    for (int m = 0; m < 8; ++m)
#pragma unroll
        for (int n = 0; n < 4; ++n) acc[m][n] = (f32x4){0.f, 0.f, 0.f, 0.f};

    const int r0 = lane & 15;
    const int rg = lane >> 4;  // k-octet within 32

    int aoff[8][2], boff[4][2];
#pragma unroll
    for (int m = 0; m < 8; ++m) {
        const int row = wm * 128 + m * 16 + r0;
#pragma unroll
        for (int ks = 0; ks < 2; ++ks)
            aoff[m][ks] = row * 64 + ((ks * 4 + rg) ^ (row & 7)) * 8;
    }
#pragma unroll
    for (int n = 0; n < 4; ++n) {
        const int col = wn * 64 + n * 16 + r0;
#pragma unroll
        for (int ks = 0; ks < 2; ++ks)
            boff[n][ks] = col * 64 + ((ks * 4 + rg) ^ (col & 7)) * 8;
    }

    auto stage = [&](int buf, int kt) {
        const size_t ko = (size_t)kt * 64;
#pragma unroll
        for (int i = 0; i < 4; ++i) {
            GLDS(Ah + offA[i] + ko, &lA[buf][sq[i] * 8]);
            GLDS(Bh + offB[i] + ko, &lB[buf][sq[i] * 8]);
        }
    };

    stage(0, 0);
    const int nK = DK / 64;  // 64
    for (int kt = 0; kt < nK; ++kt) {
        const int cur = kt & 1;
        if (kt + 1 < nK) {
            stage(cur ^ 1, kt + 1);                           // 8 new loads in flight
            asm volatile("s_waitcnt vmcnt(8)" ::: "memory");  // cur's 8 done
        } else {
            asm volatile("s_waitcnt vmcnt(0)" ::: "memory");
        }
        __builtin_amdgcn_s_barrier();

        short8 bh[4][2];
#pragma unroll
        for (int n = 0; n < 4; ++n)
#pragma unroll
            for (int ks = 0; ks < 2; ++ks) bh[n][ks] = *(const short8*)&lB[cur][boff[n][ks]];
#pragma unroll
        for (int m = 0; m < 8; ++m) {
            const short8 a0 = *(const short8*)&lA[cur][aoff[m][0]];
            const short8 a1 = *(const short8*)&lA[cur][aoff[m][1]];
#pragma unroll
            for (int n = 0; n < 4; ++n)
                acc[m][n] = __builtin_amdgcn_mfma_f32_16x16x32_bf16(a0, bh[n][0], acc[m][n], 0, 0, 0);
#pragma unroll
            for (int n = 0; n < 4; ++n)
                acc[m][n] = __builtin_amdgcn_mfma_f32_16x16x32_bf16(a1, bh[n][1], acc[m][n], 0, 0, 0);
        }
        __builtin_amdgcn_s_barrier();
    }

    // epilogue: per (m,j) row, per-block top-2 over the wave's 64 cols.
    // C/D layout col=lane&15, row=(lane>>4)*4+j [m89]
    const int rowb = by * 256 + wm * 128;
#pragma unroll
    for (int m = 0; m < 8; ++m) {
#pragma unroll
        for (int j = 0; j < 4; ++j) {
            float v1 = acc[m][0][j];
            int i1 = bx * 256 + wn * 64 + r0;
            float v2 = -3.402823466e+38f;
#pragma unroll
            for (int n = 1; n < 4; ++n) {
                const float v = acc[m][n][j];
                const int c = bx * 256 + wn * 64 + n * 16 + r0;
                if (v > v1) { v2 = v1; v1 = v; i1 = c; }
                else { v2 = fmaxf(v2, v); }
            }
#pragma unroll
            for (int off = 1; off < 16; off <<= 1) {
                const float o1 = __shfl_xor(v1, off, 64);
                const int oi = __shfl_xor(i1, off, 64);
                const float o2 = __shfl_xor(v2, off, 64);
                if (o1 > v1 || (o1 == v1 && oi < i1)) { v2 = fmaxf(v1, o2); v1 = o1; i1 = oi; }
                else { v2 = fmaxf(v2, o1); }
            }
            const int row = rowb + m * 16 + rg * 4 + j;
            if (r0 == 0)
                cand[(size_t)row * 16 + bx * 4 + wn] = make_float4(v1, (float)i1, v2, 0.f);
            if (bx == 0 && wn == 0 && r0 < 2) s01[row * 2 + r0] = acc[m][0][j];
        }
    }
}

// ---------------- finalize pass 1: merge strips, flag close rows ----------------
__global__ void __launch_bounds__(256) finalizeA_kernel(const float4* __restrict__ cand,
                                                        const float* __restrict__ s01,
                                                        float* __restrict__ out,
                                                        int* __restrict__ wl,
                                                        int* __restrict__ wc) {
    const int row = blockIdx.x * 256 + threadIdx.x;
    const float4* c = cand + (size_t)row * 16;
    float4 c0 = c[0];
    float M = c0.x, iM = c0.y, M2 = c0.z;
#pragma unroll
    for (int k = 1; k < 16; ++k) {
        const float4 ck = c[k];
        if (ck.x > M) { M2 = fmaxf(M, ck.z); M = ck.x; iM = ck.y; }
        else { M2 = fmaxf(M2, ck.x); }
    }
    out[row] = iM;
    out[NQ + row] = (s01[row * 2 + 1] - s01[row * 2 + 0]) * 0.25f + 0.5f;
    if (M - M2 < TAU) {
        const int p = atomicAdd(wc, 1);
        wl[p] = row;
    }
}

// ---------------- pass 2: 3-term recheck on flagged rows ----------------
// 32x256 tile, 4 waves (each 32x64), single-buffer LDS (36 KB), syncthreads
// loop. Arithmetic per-acc identical to the proven R3 3-term path.
__global__ void __launch_bounds__(256) gemm2_kernel(const ushort_t* __restrict__ Ah,
                                                    const ushort_t* __restrict__ Al,
                                                    const ushort_t* __restrict__ Bh,
                                                    const ushort_t* __restrict__ Bl,
                                                    const int* __restrict__ wl,
                                                    const int* __restrict__ wc,
                                                    float2* __restrict__ cand2) {
    const int cnt = *wc;
    const int by = blockIdx.y;  // slot block (32 rows)
    const int bx = blockIdx.x;  // 256-col block
    if (by * 32 >= cnt) return;

    __shared__ __align__(16) ushort_t lAh[32 * 32];
    __shared__ __align__(16) ushort_t lAl[32 * 32];
    __shared__ __align__(16) ushort_t lBh[256 * 32];
    __shared__ __align__(16) ushort_t lBl[256 * 32];

    const int tid = threadIdx.x;
    const int lane = tid & 63;
    const int w = tid >> 6;  // 0..3
    const int r0 = lane & 15;
    const int rg = lane >> 4;

    // A staging: 32 rows x 4 slots = 128 chunks; threads 0..127 (waves 0,1)
    const bool hasA = tid < 128;
    size_t offA = 0;
    if (hasA) {
        const int row = tid >> 2, sl = tid & 3;
        const int gs = sl ^ ((row >> 1) & 3);
        const int arow = wl[min(by * 32 + row, cnt - 1)];
        offA = (size_t)arow * DK + gs * 8;
    }
    // B staging: 1024 chunks; 4/thread
    size_t offB[4];
#pragma unroll
    for (int i = 0; i < 4; ++i) {
        const int q = tid + i * 256;
        const int row = q >> 2, sl = q & 3;
        const int gs = sl ^ ((row >> 1) & 3);
        offB[i] = (size_t)(bx * 256 + row) * DK + gs * 8;
    }

    f32x4 acc[2][4];
#pragma unroll
    for (int m = 0; m < 2; ++m)
#pragma unroll
        for (int n = 0; n < 4; ++n) acc[m][n] = (f32x4){0.f, 0.f, 0.f, 0.f};

    int aoff[2], boff[4];
#pragma unroll
    for (int m = 0; m < 2; ++m) {
        const int row = m * 16 + r0;
        aoff[m] = row * 32 + (rg ^ ((row >> 1) & 3)) * 8;
    }
#pragma unroll
    for (int n = 0; n < 4; ++n) {
        const int col = w * 64 + n * 16 + r0;
        boff[n] = col * 32 + (rg ^ ((col >> 1) & 3)) * 8;
    }

    for (int kt = 0; kt < DK / 32; ++kt) {
        const size_t ko = (size_t)kt * 32;
        if (hasA) {
            GLDS(Ah + offA + ko, &lAh[tid * 8]);
            GLDS(Al + offA + ko, &lAl[tid * 8]);
        }
#pragma unroll
        for (int i = 0; i < 4; ++i) {
            GLDS(Bh + offB[i] + ko, &lBh[(tid + i * 256) * 8]);
            GLDS(Bl + offB[i] + ko, &lBl[(tid + i * 256) * 8]);
        }
        __syncthreads();

        short8 bh[4], bl[4];
#pragma unroll
        for (int n = 0; n < 4; ++n) {
            bh[n] = *(const short8*)&lBh[boff[n]];
            bl[n] = *(const short8*)&lBl[boff[n]];
        }
#pragma unroll
        for (int m = 0; m < 2; ++m) {
            const short8 ah = *(const short8*)&lAh[aoff[m]];
            const short8 al = *(const short8*)&lAl[aoff[m]];
#pragma unroll
            for (int n = 0; n < 4; ++n) {
                acc[m][n] = __builtin_amdgcn_mfma_f32_16x16x32_bf16(ah, bh[n], acc[m][n], 0, 0, 0);
                acc[m][n] = __builtin_amdgcn_mfma_f32_16x16x32_bf16(ah, bl[n], acc[m][n], 0, 0, 0);
                acc[m][n] = __builtin_amdgcn_mfma_f32_16x16x32_bf16(al, bh[n], acc[m][n], 0, 0, 0);
            }
        }
        __syncthreads();
    }

    // epilogue: per (m,j) local row, argmax over wave's 64 cols
#pragma unroll
    for (int m = 0; m < 2; ++m) {
#pragma unroll
        for (int j = 0; j < 4; ++j) {
            float best = acc[m][0][j];
            int bidx = bx * 256 + w * 64 + r0;
#pragma unroll
            for (int n = 1; n < 4; ++n) {
                const float v = acc[m][n][j];
                const int c = bx * 256 + w * 64 + n * 16 + r0;
                if (v > best) { best = v; bidx = c; }
            }
#pragma unroll
            for (int off = 1; off < 16; off <<= 1) {
                const float ov = __shfl_xor(best, off, 64);
                const int oi = __shfl_xor(bidx, off, 64);
                if (ov > best || (ov == best && oi < bidx)) { best = ov; bidx = oi; }
            }
            const int lrow = m * 16 + rg * 4 + j;
            const int slotg = by * 32 + lrow;
            if (r0 == 0 && slotg < cnt)
                cand2[(size_t)slotg * 16 + bx * 4 + w] = make_float2(best, (float)bidx);
        }
    }
}

// ---------------- finalize pass 2 ----------------
__global__ void __launch_bounds__(256) finalizeB_kernel(const float2* __restrict__ cand2,
                                                        const int* __restrict__ wl,
                                                        const int* __restrict__ wc,
                                                        float* __restrict__ out) {
    const int slot = blockIdx.x * 256 + threadIdx.x;
    const int cnt = *wc;
    if (slot >= cnt) return;
    const int row = wl[slot];
    const float2* c = cand2 + (size_t)slot * 16;
    float best = c[0].x;
    float bi = c[0].y;
#pragma unroll
    for (int k = 1; k < 16; ++k) {
        const float2 p = c[k];
        if (p.x > best) { best = p.x; bi = p.y; }  // ascending cols: strict > keeps first
    }
    out[row] = bi;
}

extern "C" void kernel_launch(void* const* d_in, const int* in_sizes, int n_in,
                              void* d_out, int out_size, void* d_ws, size_t ws_size,
                              hipStream_t stream) {
    const float* hvs = (const float*)d_in[0];  // [16384,4096] f32
    const float* am  = (const float*)d_in[1];  // [1024,4096] f32
    float* out = (float*)d_out;                // [preds | eta]

    ushort_t* Bh = (ushort_t*)d_ws;                    // 8 MB
    ushort_t* Bl = Bh + (size_t)NC * DK;               // 8 MB
    ushort_t* Ah = Bl + (size_t)NC * DK;               // 128 MB
    ushort_t* Al = Ah + (size_t)NQ * DK;               // 128 MB
    float4* cand = (float4*)(Al + (size_t)NQ * DK);    // 4 MB
    float* s01 = (float*)(cand + (size_t)NQ * 16);     // 128 KB
    float2* cand2 = (float2*)(s01 + (size_t)NQ * 2);   // 2 MB
    int* wl = (int*)(cand2 + (size_t)NQ * 16);         // 64 KB
    int* wc = wl + NQ;                                 // 4 B

    hipMemsetAsync(wc, 0, sizeof(int), stream);
    norm_split_kernel<<<NC, 256, 0, stream>>>(am, Bh, Bl);
    norm_split_kernel<<<NQ, 256, 0, stream>>>(hvs, Ah, Al);
    gemm1_kernel<<<256, 512, 0, stream>>>(Ah, Bh, cand, s01);
    finalizeA_kernel<<<NQ / 256, 256, 0, stream>>>(cand, s01, out, wl, wc);
    gemm2_kernel<<<dim3(4, NQ / 32), 256, 0, stream>>>(Ah, Al, Bh, Bl, wl, wc, cand2);
    finalizeB_kernel<<<NQ / 256, 256, 0, stream>>>(cand2, wl, wc, out);
}